// Round 7
// baseline (447.566 us; speedup 1.0000x reference)
//
#include <hip/hip_runtime.h>
#include <hip/hip_bf16.h>

#define NN 50000
#define EE 800000
#define ET (EE + NN)
#define F_IN 128
#define HID 32
#define H1 4
#define H2 8
#define E_DEC 100000
#define NEG_SLOPE 0.2f

typedef __attribute__((ext_vector_type(8))) short short8;
typedef __attribute__((ext_vector_type(4))) float floatx4;

__device__ __forceinline__ unsigned short f2b(float f) {
    __hip_bfloat16 h = __float2bfloat16(f);
    return *reinterpret_cast<unsigned short*>(&h);
}
__device__ __forceinline__ float b2f(unsigned short u) {
    return __uint_as_float(((unsigned int)u) << 16);
}

// ============ merged: XCD-local histogram+rank + pack W1 + pack W2 ============
__device__ __forceinline__ void packW_one(const float* __restrict__ W,
                                          unsigned short* __restrict__ Wp, int OUT, int id) {
    const int ctg = id >> 8;
    const int ln = id & 63;
    const int col = ctg * 16 + (ln & 15);
    const int k0 = ((id >> 6) & 3) * 32 + ((ln >> 4) & 3) * 8;
    ushort4 lo, hi;
    lo.x = f2b(W[(k0 + 0) * OUT + col]);
    lo.y = f2b(W[(k0 + 1) * OUT + col]);
    lo.z = f2b(W[(k0 + 2) * OUT + col]);
    lo.w = f2b(W[(k0 + 3) * OUT + col]);
    hi.x = f2b(W[(k0 + 4) * OUT + col]);
    hi.y = f2b(W[(k0 + 5) * OUT + col]);
    hi.z = f2b(W[(k0 + 6) * OUT + col]);
    hi.w = f2b(W[(k0 + 7) * OUT + col]);
    ((ushort4*)Wp)[id * 2] = lo;
    ((ushort4*)Wp)[id * 2 + 1] = hi;
}

#define HIST_BLOCKS ((EE / 4 + 255) / 256)   // 782
#define PACK_BLOCKS ((6144 + 255) / 256)     // 24

__global__ void hist_pack_k(const int* __restrict__ ei, int* __restrict__ counts_p,
                            const int* __restrict__ probe, int* __restrict__ rank,
                            const float* __restrict__ W1, unsigned short* __restrict__ wp1,
                            const float* __restrict__ W2, unsigned short* __restrict__ wp2) {
    if (blockIdx.x < HIST_BLOCKS) {
        const int t = blockIdx.x * 256 + threadIdx.x;
        if (t >= EE / 4) return;
        const int pv = probe[0];
        int* cp = counts_p + (blockIdx.x & 7) * NN;
        const int4 d4 = ((const int4*)(ei + EE))[t];
        int4 r4;
        r4.x = atomicAdd(&cp[d4.x], 1) - pv;
        r4.y = atomicAdd(&cp[d4.y], 1) - pv;
        r4.z = atomicAdd(&cp[d4.z], 1) - pv;
        r4.w = atomicAdd(&cp[d4.w], 1) - pv;
        ((int4*)rank)[t] = r4;
    } else {
        const int id = (blockIdx.x - HIST_BLOCKS) * 256 + threadIdx.x;
        if (id < 2048) packW_one(W1, wp1, 128, id);
        else if (id < 6144) packW_one(W2, wp2, 256, id - 2048);
    }
}

// ============ hierarchical exclusive scan over node degrees ============
__global__ void scan1_k(const int* __restrict__ counts_p, const int* __restrict__ probe,
                        int* __restrict__ bsum) {
    __shared__ int sh[256];
    const unsigned pv = (unsigned)probe[0];
    int t = threadIdx.x;
    int i = blockIdx.x * 256 + t;
    int deg = 0;
    if (i < NN) {
        unsigned sum = 0;
#pragma unroll
        for (int s = 0; s < 8; ++s) sum += (unsigned)counts_p[s * NN + i];
        deg = (int)(sum - 8u * pv) + 1;
    }
    sh[t] = deg;
    __syncthreads();
    for (int off = 128; off > 0; off >>= 1) {
        if (t < off) sh[t] += sh[t + off];
        __syncthreads();
    }
    if (t == 0) bsum[blockIdx.x] = sh[0];
}

__global__ void scan2_k(int* __restrict__ bsum, int nb, int* __restrict__ start) {
    __shared__ int sh[256];
    int t = threadIdx.x;
    int v = (t < nb) ? bsum[t] : 0;
    sh[t] = v;
    __syncthreads();
    for (int off = 1; off < 256; off <<= 1) {
        int u = (t >= off) ? sh[t - off] : 0;
        __syncthreads();
        sh[t] += u;
        __syncthreads();
    }
    if (t < nb) bsum[t] = sh[t] - v;
    if (t == 0) start[NN] = ET;
}

// ============ scan3: start/offs/self-loop + BLOCK-LOCAL degree counting-sort ============
// perm[b*256 + lpos] lists block b's nodes sorted by degree. Local sort keeps
// all of a gather wave's csr/start/out accesses inside a 256-node window
// (locality of r3) while giving waves 8 near-equal-degree nodes (balance of r6).
__global__ void scan3_k(const int* __restrict__ counts_p, const int* __restrict__ probe,
                        const int* __restrict__ bsum, int* __restrict__ start,
                        int* __restrict__ offs, int* __restrict__ csr,
                        int* __restrict__ perm) {
    __shared__ int sh[256];
    __shared__ int lhist[256];
    const unsigned pv = (unsigned)probe[0];
    int t = threadIdx.x;
    int i = blockIdx.x * 256 + t;
    lhist[t] = 0;
    int part[8];
    int deg = 0;
    if (i < NN) {
        deg = 1;
#pragma unroll
        for (int s = 0; s < 8; ++s) {
            part[s] = (int)((unsigned)counts_p[s * NN + i] - pv);
            deg += part[s];
        }
    }
    const int bin = deg < 255 ? deg : 255;
    sh[t] = deg;
    __syncthreads();
    int lrank = 0;
    if (i < NN) lrank = atomicAdd(&lhist[bin], 1);   // LDS atomic: local rank in bin
    for (int off = 1; off < 256; off <<= 1) {
        int u = (t >= off) ? sh[t - off] : 0;
        __syncthreads();
        sh[t] += u;
        __syncthreads();
    }
    int excl = sh[t] - deg + bsum[blockIdx.x];
    if (i < NN) {
        start[i] = excl;
        int o = excl;
#pragma unroll
        for (int s = 0; s < 8; ++s) {
            offs[s * NN + i] = o;
            o += part[s];
        }
        csr[o] = i;   // self-loop last
    }
    // block-local exclusive scan over lhist -> bin bases; perm = local counting sort
    __syncthreads();
    const int hv = lhist[t];
    sh[t] = hv;
    __syncthreads();
    for (int off = 1; off < 256; off <<= 1) {
        int u = (t >= off) ? sh[t - off] : 0;
        __syncthreads();
        sh[t] += u;
        __syncthreads();
    }
    if (i < NN) {
        const int lpos = sh[bin] - lhist[bin] + lrank;   // exclusive base + rank
        perm[blockIdx.x * 256 + lpos] = i;
    }
}

// ============ scatter: rank+offs based, NO atomics, XCD-affine offs reads ============
__global__ void scatter_k(const int* __restrict__ ei, const int* __restrict__ rank,
                          const int* __restrict__ offs, int* __restrict__ csr) {
    const int t = blockIdx.x * 256 + threadIdx.x;
    if (t >= EE / 4) return;
    const int* off = offs + (blockIdx.x & 7) * NN;
    const int4 s4 = ((const int4*)ei)[t];
    const int4 d4 = ((const int4*)(ei + EE))[t];
    const int4 r4 = ((const int4*)rank)[t];
    csr[off[d4.x] + r4.x] = s4.x;
    csr[off[d4.y] + r4.y] = s4.y;
    csr[off[d4.z] + r4.z] = s4.z;
    csr[off[d4.w] + r4.w] = s4.w;
}

// ============ MFMA GEMM + fused al epilogue ============
// Hout SLAB-MAJOR [head][NN][32ch]; als/ald HEAD-MAJOR [H][NN].
template <int OUT, int H, int CT, bool F32IN>
__global__ void gemm_k(const void* __restrict__ Xin, const unsigned short* __restrict__ Wp,
                       const float* __restrict__ a_src, const float* __restrict__ a_dst,
                       unsigned short* __restrict__ Hout, float* __restrict__ als,
                       float* __restrict__ ald) {
    const int wave = threadIdx.x >> 6;
    const int lane = threadIdx.x & 63;
    const int quad = lane >> 4;
    const int rl = lane & 15;
    const int r0 = blockIdx.x * 64;
    floatx4 acc[4][CT];
#pragma unroll
    for (int rt = 0; rt < 4; ++rt)
#pragma unroll
        for (int ct = 0; ct < CT; ++ct) acc[rt][ct] = {0.f, 0.f, 0.f, 0.f};

#pragma unroll
    for (int ks = 0; ks < 4; ++ks) {
        short8 a[4];
        const int c0k = ks * 32 + quad * 8;
#pragma unroll
        for (int rt = 0; rt < 4; ++rt) {
            int row = r0 + rt * 16 + rl;
            row = row < NN ? row : NN - 1;
            if (F32IN) {
                const float4* xp =
                    (const float4*)((const float*)Xin + (long long)row * 128 + c0k);
                const float4 v0 = xp[0];
                const float4 v1 = xp[1];
                short8 tt;
                tt[0] = (short)f2b(v0.x);
                tt[1] = (short)f2b(v0.y);
                tt[2] = (short)f2b(v0.z);
                tt[3] = (short)f2b(v0.w);
                tt[4] = (short)f2b(v1.x);
                tt[5] = (short)f2b(v1.y);
                tt[6] = (short)f2b(v1.z);
                tt[7] = (short)f2b(v1.w);
                a[rt] = tt;
            } else {
                a[rt] = *(const short8*)((const unsigned short*)Xin +
                                         (long long)row * 128 + c0k);
            }
        }
#pragma unroll
        for (int ct = 0; ct < CT; ++ct) {
            const int ctg = wave * CT + ct;
            const short8 b = *(const short8*)(Wp + (((ctg * 4 + ks) * 64 + lane) << 3));
#pragma unroll
            for (int rt = 0; rt < 4; ++rt)
                acc[rt][ct] = __builtin_amdgcn_mfma_f32_16x16x32_bf16(a[rt], b, acc[rt][ct], 0, 0, 0);
        }
    }
#pragma unroll
    for (int rt = 0; rt < 4; ++rt) {
        const int rowbase = r0 + rt * 16 + quad * 4;
#pragma unroll
        for (int ct = 0; ct < CT; ++ct) {
            const int col = (wave * CT + ct) * 16 + rl;
            unsigned short* hp = Hout + (long long)(col >> 5) * NN * 32 + (col & 31);
#pragma unroll
            for (int r = 0; r < 4; ++r) {
                const int row = rowbase + r;
                if (row < NN) hp[(long long)row * 32] = f2b(acc[rt][ct][r]);
            }
        }
    }
    float asv[CT], adv[CT];
#pragma unroll
    for (int ct = 0; ct < CT; ++ct) {
        const int col = (wave * CT + ct) * 16 + rl;
        asv[ct] = a_src[col];
        adv[ct] = a_dst[col];
    }
#pragma unroll
    for (int rt = 0; rt < 4; ++rt) {
#pragma unroll
        for (int r = 0; r < 4; ++r) {
            const int row = r0 + rt * 16 + quad * 4 + r;
            float ps[CT / 2], pd[CT / 2];
#pragma unroll
            for (int hh = 0; hh < CT / 2; ++hh) {
                ps[hh] = acc[rt][2 * hh][r] * asv[2 * hh] + acc[rt][2 * hh + 1][r] * asv[2 * hh + 1];
                pd[hh] = acc[rt][2 * hh][r] * adv[2 * hh] + acc[rt][2 * hh + 1][r] * adv[2 * hh + 1];
#pragma unroll
                for (int m = 8; m >= 1; m >>= 1) {
                    ps[hh] += __shfl_xor(ps[hh], m, 64);
                    pd[hh] += __shfl_xor(pd[hh], m, 64);
                }
            }
            if (rl == 0 && row < NN) {
#pragma unroll
                for (int hh = 0; hh < CT / 2; ++hh) {
                    const int hd = wave * (CT / 2) + hh;
                    als[(long long)hd * NN + row] = ps[hh];
                    ald[(long long)hd * NN + row] = pd[hh];
                }
            }
        }
    }
}

// ============ XCD-sliced gather, block-locally degree-sorted groups ============
// Slice s (= head) pinned to XCD(s) via blockIdx&7; 3.2 MB slab L2-resident.
// 8-lane group owns one (node, slice); node = perm[gidx] where perm is sorted
// by degree WITHIN each 256-node block: equal-degree groups (no divergence)
// AND all csr/start/out accesses stay in a 256-node window (locality).
template <int OUT, int NSLICE, bool RELU>
__global__ void gathers_k(const int* __restrict__ start, const int* __restrict__ csr,
                          const int* __restrict__ perm,
                          const float* __restrict__ als, const float* __restrict__ ald,
                          const unsigned short* __restrict__ Hin,
                          const float* __restrict__ bias, unsigned short* __restrict__ outp) {
    constexpr int SUB = 8 / NSLICE;        // XCDs per slice
    const int xcd = blockIdx.x & 7;
    const int s = xcd / SUB;               // slice == head
    const int sub = xcd & (SUB - 1);
    const int wave = threadIdx.x >> 6;
    const int lane = threadIdx.x & 63;
    const int g = lane >> 3;               // group (node) within wave
    const int cl = lane & 7;               // channel lane (4 ch each)
    const int gidx = (blockIdx.x >> 3) * (32 * SUB) + sub * 32 + wave * 8 + g;
    if (gidx >= NN) return;
    const int d = perm[gidx];
    const float* als_h = als + s * NN;
    const float aldd = ald[s * NN + d];
    const unsigned short* slab = Hin + s * (NN * 32);
    const int beg = start[d], end = start[d + 1];
    float a0 = 0.f, a1 = 0.f, a2 = 0.f, a3 = 0.f, den = 0.f;
    int i = beg;
    for (; i + 7 < end; i += 8) {
        int sn[8];
        float l[8];
        ushort4 hv[8];
#pragma unroll
        for (int k = 0; k < 8; ++k) sn[k] = __builtin_nontemporal_load(csr + i + k);
#pragma unroll
        for (int k = 0; k < 8; ++k) l[k] = als_h[sn[k]] + aldd;
#pragma unroll
        for (int k = 0; k < 8; ++k) hv[k] = *(const ushort4*)(slab + sn[k] * 32 + cl * 4);
#pragma unroll
        for (int k = 0; k < 8; ++k) {
            float lg = l[k] > 0.f ? l[k] : NEG_SLOPE * l[k];
            const float w = __expf(lg);
            den += w;
            a0 += w * b2f(hv[k].x);
            a1 += w * b2f(hv[k].y);
            a2 += w * b2f(hv[k].z);
            a3 += w * b2f(hv[k].w);
        }
    }
    for (; i + 3 < end; i += 4) {
        int sn[4];
        float l[4];
        ushort4 hv[4];
#pragma unroll
        for (int k = 0; k < 4; ++k) sn[k] = __builtin_nontemporal_load(csr + i + k);
#pragma unroll
        for (int k = 0; k < 4; ++k) l[k] = als_h[sn[k]] + aldd;
#pragma unroll
        for (int k = 0; k < 4; ++k) hv[k] = *(const ushort4*)(slab + sn[k] * 32 + cl * 4);
#pragma unroll
        for (int k = 0; k < 4; ++k) {
            float lg = l[k] > 0.f ? l[k] : NEG_SLOPE * l[k];
            const float w = __expf(lg);
            den += w;
            a0 += w * b2f(hv[k].x);
            a1 += w * b2f(hv[k].y);
            a2 += w * b2f(hv[k].z);
            a3 += w * b2f(hv[k].w);
        }
    }
    for (; i < end; ++i) {
        const int sn = __builtin_nontemporal_load(csr + i);
        float lg = als_h[sn] + aldd;
        lg = lg > 0.f ? lg : NEG_SLOPE * lg;
        const float w = __expf(lg);
        const ushort4 hv = *(const ushort4*)(slab + sn * 32 + cl * 4);
        den += w;
        a0 += w * b2f(hv.x);
        a1 += w * b2f(hv.y);
        a2 += w * b2f(hv.z);
        a3 += w * b2f(hv.w);
    }
    const float inv = 1.f / (den + 1e-16f);
    const int c0 = s * 32 + cl * 4;
    float v0 = a0 * inv + bias[c0];
    float v1 = a1 * inv + bias[c0 + 1];
    float v2 = a2 * inv + bias[c0 + 2];
    float v3 = a3 * inv + bias[c0 + 3];
    if (RELU) {
        v0 = v0 > 0.f ? v0 : 0.f;
        v1 = v1 > 0.f ? v1 : 0.f;
        v2 = v2 > 0.f ? v2 : 0.f;
        v3 = v3 > 0.f ? v3 : 0.f;
    }
    unsigned long long pk =
        (unsigned long long)f2b(v0) |
        ((unsigned long long)f2b(v1) << 16) |
        ((unsigned long long)f2b(v2) << 32) |
        ((unsigned long long)f2b(v3) << 48);
    __builtin_nontemporal_store(pk, (unsigned long long*)(outp + d * OUT + c0));
}

// ============ decode: XCD-sliced partial dots ============
__global__ void decode_s_k(const int* __restrict__ pei, const int* __restrict__ nei,
                           const unsigned short* __restrict__ z2, float* __restrict__ part) {
    const int s = blockIdx.x & 7;
    const int g = blockIdx.x >> 3;
    const int wave = threadIdx.x >> 6, lane = threadIdx.x & 63;
    const int slot = lane >> 3, cl = lane & 7;
    const int idx = g * 32 + wave * 8 + slot;
    if (idx >= 2 * E_DEC) return;
    int a, b;
    if (idx < E_DEC) {
        a = pei[idx];
        b = pei[E_DEC + idx];
    } else {
        const int j = idx - E_DEC;
        a = nei[j];
        b = nei[E_DEC + j];
    }
    const ushort4 ua = *(const ushort4*)(z2 + (long long)a * 256 + s * 32 + cl * 4);
    const ushort4 ub = *(const ushort4*)(z2 + (long long)b * 256 + s * 32 + cl * 4);
    float sum = b2f(ua.x) * b2f(ub.x) + b2f(ua.y) * b2f(ub.y) +
                b2f(ua.z) * b2f(ub.z) + b2f(ua.w) * b2f(ub.w);
    sum += __shfl_xor(sum, 4, 64);
    sum += __shfl_xor(sum, 2, 64);
    sum += __shfl_xor(sum, 1, 64);
    if (cl == 0) part[(long long)s * (2 * E_DEC) + idx] = sum;
}

__global__ void reduce_k(const float* __restrict__ part, float* __restrict__ out) {
    const int i = blockIdx.x * 256 + threadIdx.x;
    if (i >= 2 * E_DEC) return;
    float s = 0.f;
#pragma unroll
    for (int k = 0; k < 8; ++k) s += part[(long long)k * (2 * E_DEC) + i];
    out[i] = s;
}

extern "C" void kernel_launch(void* const* d_in, const int* in_sizes, int n_in,
                              void* d_out, int out_size, void* d_ws, size_t ws_size,
                              hipStream_t stream) {
    const float* x = (const float*)d_in[0];
    const int* ei = (const int*)d_in[1];
    const int* pei = (const int*)d_in[2];
    const int* nei = (const int*)d_in[3];
    const float* W1 = (const float*)d_in[4];
    const float* as1 = (const float*)d_in[5];
    const float* ad1 = (const float*)d_in[6];
    const float* b1 = (const float*)d_in[7];
    const float* W2 = (const float*)d_in[8];
    const float* as2 = (const float*)d_in[9];
    const float* ad2 = (const float*)d_in[10];
    const float* b2 = (const float*)d_in[11];
    float* out = (float*)d_out;

    // ---- workspace layout ----
    unsigned short* h1 = (unsigned short*)d_ws;              // [4][NN][32] slab-major
    unsigned short* h2 = h1 + (long long)NN * 128;           // [8][NN][32] slab-major
    unsigned short* z2 = h2 + (long long)NN * 256;           // NN*256 row-major
    unsigned short* z1 = z2 + (long long)NN * 256;           // NN*128 row-major
    unsigned short* wp1 = z1 + (long long)NN * 128;          // 128*128
    unsigned short* wp2 = wp1 + 128 * 128;                   // 128*256
    float* als1 = (float*)(wp2 + 128 * 256);                 // [H1][NN] head-major
    float* ald1 = als1 + NN * H1;
    float* als2 = ald1 + NN * H1;                            // [H2][NN] head-major
    float* ald2 = als2 + NN * H2;
    float* part = ald2 + NN * H2;                            // 8 * 2*E_DEC
    int* counts_p = (int*)(part + 8 * 2 * E_DEC);            // 8*NN
    int* start = counts_p + 8 * NN;                          // NN+1
    int* offs = start + NN + 1;                              // 8*NN
    int* rank = offs + 8 * NN;                               // EE
    int* bsum = rank + EE;                                   // 256
    int* csr = bsum + 256;                                   // ET
    int* perm = csr + ET;                                    // NN (block-local degree sort)
    int* probe = perm + NN;                                  // 1 (never written)

    const int NB = (NN + 255) / 256;  // 196

    // ---- CSR build + W pack + block-local degree sort ----
    hist_pack_k<<<HIST_BLOCKS + PACK_BLOCKS, 256, 0, stream>>>(
        ei, counts_p, probe, rank, W1, wp1, W2, wp2);
    scan1_k<<<NB, 256, 0, stream>>>(counts_p, probe, bsum);
    scan2_k<<<1, 256, 0, stream>>>(bsum, NB, start);
    scan3_k<<<NB, 256, 0, stream>>>(counts_p, probe, bsum, start, offs, csr, perm);
    scatter_k<<<HIST_BLOCKS, 256, 0, stream>>>(ei, rank, offs, csr);

    // ---- conv1 ----
    gemm_k<128, H1, 2, true><<<(NN + 63) / 64, 256, 0, stream>>>(
        x, wp1, as1, ad1, h1, als1, ald1);
    // 4 slices, 2 XCDs each; block covers 32 nodes of one slice (64 per pair)
    gathers_k<128, 4, true><<<8 * ((NN + 63) / 64), 256, 0, stream>>>(
        start, csr, perm, als1, ald1, h1, b1, z1);

    // ---- conv2 ----
    gemm_k<256, H2, 4, false><<<(NN + 63) / 64, 256, 0, stream>>>(
        z1, wp2, as2, ad2, h2, als2, ald2);
    // 8 slices, 1 XCD each; block covers 32 nodes of one slice
    gathers_k<256, 8, false><<<8 * ((NN + 31) / 32), 256, 0, stream>>>(
        start, csr, perm, als2, ald2, h2, b2, z2);

    // ---- decode ----
    decode_s_k<<<8 * ((2 * E_DEC + 31) / 32), 256, 0, stream>>>(pei, nei, z2, part);
    reduce_k<<<(2 * E_DEC + 255) / 256, 256, 0, stream>>>(part, out);
}

// Round 8
// 371.870 us; speedup vs baseline: 1.2036x; 1.2036x over previous
//
#include <hip/hip_runtime.h>
#include <hip/hip_bf16.h>

#define NN 50000
#define EE 800000
#define ET (EE + NN)
#define F_IN 128
#define HID 32
#define H1 4
#define H2 8
#define E_DEC 100000
#define NEG_SLOPE 0.2f
#define WCAP 5888   // staged csr capacity per 256-node window (mean 4608, +19 sigma)

typedef __attribute__((ext_vector_type(8))) short short8;
typedef __attribute__((ext_vector_type(4))) float floatx4;

__device__ __forceinline__ unsigned short f2b(float f) {
    __hip_bfloat16 h = __float2bfloat16(f);
    return *reinterpret_cast<unsigned short*>(&h);
}
__device__ __forceinline__ float b2f(unsigned short u) {
    return __uint_as_float(((unsigned int)u) << 16);
}

// ============ merged: XCD-local histogram+rank + pack W1 + pack W2 ============
__device__ __forceinline__ void packW_one(const float* __restrict__ W,
                                          unsigned short* __restrict__ Wp, int OUT, int id) {
    const int ctg = id >> 8;
    const int ln = id & 63;
    const int col = ctg * 16 + (ln & 15);
    const int k0 = ((id >> 6) & 3) * 32 + ((ln >> 4) & 3) * 8;
    ushort4 lo, hi;
    lo.x = f2b(W[(k0 + 0) * OUT + col]);
    lo.y = f2b(W[(k0 + 1) * OUT + col]);
    lo.z = f2b(W[(k0 + 2) * OUT + col]);
    lo.w = f2b(W[(k0 + 3) * OUT + col]);
    hi.x = f2b(W[(k0 + 4) * OUT + col]);
    hi.y = f2b(W[(k0 + 5) * OUT + col]);
    hi.z = f2b(W[(k0 + 6) * OUT + col]);
    hi.w = f2b(W[(k0 + 7) * OUT + col]);
    ((ushort4*)Wp)[id * 2] = lo;
    ((ushort4*)Wp)[id * 2 + 1] = hi;
}

#define HIST_BLOCKS ((EE / 4 + 255) / 256)   // 782
#define PACK_BLOCKS ((6144 + 255) / 256)     // 24

__global__ void hist_pack_k(const int* __restrict__ ei, int* __restrict__ counts_p,
                            const int* __restrict__ probe, int* __restrict__ rank,
                            const float* __restrict__ W1, unsigned short* __restrict__ wp1,
                            const float* __restrict__ W2, unsigned short* __restrict__ wp2) {
    if (blockIdx.x < HIST_BLOCKS) {
        const int t = blockIdx.x * 256 + threadIdx.x;
        if (t >= EE / 4) return;
        const int pv = probe[0];
        int* cp = counts_p + (blockIdx.x & 7) * NN;
        const int4 d4 = ((const int4*)(ei + EE))[t];
        int4 r4;
        r4.x = atomicAdd(&cp[d4.x], 1) - pv;
        r4.y = atomicAdd(&cp[d4.y], 1) - pv;
        r4.z = atomicAdd(&cp[d4.z], 1) - pv;
        r4.w = atomicAdd(&cp[d4.w], 1) - pv;
        ((int4*)rank)[t] = r4;
    } else {
        const int id = (blockIdx.x - HIST_BLOCKS) * 256 + threadIdx.x;
        if (id < 2048) packW_one(W1, wp1, 128, id);
        else if (id < 6144) packW_one(W2, wp2, 256, id - 2048);
    }
}

// ============ hierarchical exclusive scan over node degrees ============
__global__ void scan1_k(const int* __restrict__ counts_p, const int* __restrict__ probe,
                        int* __restrict__ bsum) {
    __shared__ int sh[256];
    const unsigned pv = (unsigned)probe[0];
    int t = threadIdx.x;
    int i = blockIdx.x * 256 + t;
    int deg = 0;
    if (i < NN) {
        unsigned sum = 0;
#pragma unroll
        for (int s = 0; s < 8; ++s) sum += (unsigned)counts_p[s * NN + i];
        deg = (int)(sum - 8u * pv) + 1;
    }
    sh[t] = deg;
    __syncthreads();
    for (int off = 128; off > 0; off >>= 1) {
        if (t < off) sh[t] += sh[t + off];
        __syncthreads();
    }
    if (t == 0) bsum[blockIdx.x] = sh[0];
}

__global__ void scan2_k(int* __restrict__ bsum, int nb, int* __restrict__ start) {
    __shared__ int sh[256];
    int t = threadIdx.x;
    int v = (t < nb) ? bsum[t] : 0;
    sh[t] = v;
    __syncthreads();
    for (int off = 1; off < 256; off <<= 1) {
        int u = (t >= off) ? sh[t - off] : 0;
        __syncthreads();
        sh[t] += u;
        __syncthreads();
    }
    if (t < nb) bsum[t] = sh[t] - v;
    if (t == 0) start[NN] = ET;
}

// ============ scan3: start/offs/self-loop + BLOCK-LOCAL degree counting-sort ============
__global__ void scan3_k(const int* __restrict__ counts_p, const int* __restrict__ probe,
                        const int* __restrict__ bsum, int* __restrict__ start,
                        int* __restrict__ offs, int* __restrict__ csr,
                        int* __restrict__ perm) {
    __shared__ int sh[256];
    __shared__ int lhist[256];
    const unsigned pv = (unsigned)probe[0];
    int t = threadIdx.x;
    int i = blockIdx.x * 256 + t;
    lhist[t] = 0;
    int part[8];
    int deg = 0;
    if (i < NN) {
        deg = 1;
#pragma unroll
        for (int s = 0; s < 8; ++s) {
            part[s] = (int)((unsigned)counts_p[s * NN + i] - pv);
            deg += part[s];
        }
    }
    const int bin = deg < 255 ? deg : 255;
    sh[t] = deg;
    __syncthreads();
    int lrank = 0;
    if (i < NN) lrank = atomicAdd(&lhist[bin], 1);   // LDS atomic: local rank in bin
    for (int off = 1; off < 256; off <<= 1) {
        int u = (t >= off) ? sh[t - off] : 0;
        __syncthreads();
        sh[t] += u;
        __syncthreads();
    }
    int excl = sh[t] - deg + bsum[blockIdx.x];
    if (i < NN) {
        start[i] = excl;
        int o = excl;
#pragma unroll
        for (int s = 0; s < 8; ++s) {
            offs[s * NN + i] = o;
            o += part[s];
        }
        csr[o] = i;   // self-loop last
    }
    // block-local exclusive scan over lhist -> bin bases; perm = local counting sort
    __syncthreads();
    const int hv = lhist[t];
    sh[t] = hv;
    __syncthreads();
    for (int off = 1; off < 256; off <<= 1) {
        int u = (t >= off) ? sh[t - off] : 0;
        __syncthreads();
        sh[t] += u;
        __syncthreads();
    }
    if (i < NN) {
        const int lpos = sh[bin] - lhist[bin] + lrank;   // exclusive base + rank
        perm[blockIdx.x * 256 + lpos] = i;
    }
}

// ============ scatter: rank+offs based, NO atomics, XCD-affine offs reads ============
__global__ void scatter_k(const int* __restrict__ ei, const int* __restrict__ rank,
                          const int* __restrict__ offs, int* __restrict__ csr) {
    const int t = blockIdx.x * 256 + threadIdx.x;
    if (t >= EE / 4) return;
    const int* off = offs + (blockIdx.x & 7) * NN;
    const int4 s4 = ((const int4*)ei)[t];
    const int4 d4 = ((const int4*)(ei + EE))[t];
    const int4 r4 = ((const int4*)rank)[t];
    csr[off[d4.x] + r4.x] = s4.x;
    csr[off[d4.y] + r4.y] = s4.y;
    csr[off[d4.z] + r4.z] = s4.z;
    csr[off[d4.w] + r4.w] = s4.w;
}

// ============ MFMA GEMM + fused al epilogue ============
// Hout SLAB-MAJOR [head][NN][32ch]; als/ald HEAD-MAJOR [H][NN].
template <int OUT, int H, int CT, bool F32IN>
__global__ void gemm_k(const void* __restrict__ Xin, const unsigned short* __restrict__ Wp,
                       const float* __restrict__ a_src, const float* __restrict__ a_dst,
                       unsigned short* __restrict__ Hout, float* __restrict__ als,
                       float* __restrict__ ald) {
    const int wave = threadIdx.x >> 6;
    const int lane = threadIdx.x & 63;
    const int quad = lane >> 4;
    const int rl = lane & 15;
    const int r0 = blockIdx.x * 64;
    floatx4 acc[4][CT];
#pragma unroll
    for (int rt = 0; rt < 4; ++rt)
#pragma unroll
        for (int ct = 0; ct < CT; ++ct) acc[rt][ct] = {0.f, 0.f, 0.f, 0.f};

#pragma unroll
    for (int ks = 0; ks < 4; ++ks) {
        short8 a[4];
        const int c0k = ks * 32 + quad * 8;
#pragma unroll
        for (int rt = 0; rt < 4; ++rt) {
            int row = r0 + rt * 16 + rl;
            row = row < NN ? row : NN - 1;
            if (F32IN) {
                const float4* xp =
                    (const float4*)((const float*)Xin + (long long)row * 128 + c0k);
                const float4 v0 = xp[0];
                const float4 v1 = xp[1];
                short8 tt;
                tt[0] = (short)f2b(v0.x);
                tt[1] = (short)f2b(v0.y);
                tt[2] = (short)f2b(v0.z);
                tt[3] = (short)f2b(v0.w);
                tt[4] = (short)f2b(v1.x);
                tt[5] = (short)f2b(v1.y);
                tt[6] = (short)f2b(v1.z);
                tt[7] = (short)f2b(v1.w);
                a[rt] = tt;
            } else {
                a[rt] = *(const short8*)((const unsigned short*)Xin +
                                         (long long)row * 128 + c0k);
            }
        }
#pragma unroll
        for (int ct = 0; ct < CT; ++ct) {
            const int ctg = wave * CT + ct;
            const short8 b = *(const short8*)(Wp + (((ctg * 4 + ks) * 64 + lane) << 3));
#pragma unroll
            for (int rt = 0; rt < 4; ++rt)
                acc[rt][ct] = __builtin_amdgcn_mfma_f32_16x16x32_bf16(a[rt], b, acc[rt][ct], 0, 0, 0);
        }
    }
#pragma unroll
    for (int rt = 0; rt < 4; ++rt) {
        const int rowbase = r0 + rt * 16 + quad * 4;
#pragma unroll
        for (int ct = 0; ct < CT; ++ct) {
            const int col = (wave * CT + ct) * 16 + rl;
            unsigned short* hp = Hout + (long long)(col >> 5) * NN * 32 + (col & 31);
#pragma unroll
            for (int r = 0; r < 4; ++r) {
                const int row = rowbase + r;
                if (row < NN) hp[(long long)row * 32] = f2b(acc[rt][ct][r]);
            }
        }
    }
    float asv[CT], adv[CT];
#pragma unroll
    for (int ct = 0; ct < CT; ++ct) {
        const int col = (wave * CT + ct) * 16 + rl;
        asv[ct] = a_src[col];
        adv[ct] = a_dst[col];
    }
#pragma unroll
    for (int rt = 0; rt < 4; ++rt) {
#pragma unroll
        for (int r = 0; r < 4; ++r) {
            const int row = r0 + rt * 16 + quad * 4 + r;
            float ps[CT / 2], pd[CT / 2];
#pragma unroll
            for (int hh = 0; hh < CT / 2; ++hh) {
                ps[hh] = acc[rt][2 * hh][r] * asv[2 * hh] + acc[rt][2 * hh + 1][r] * asv[2 * hh + 1];
                pd[hh] = acc[rt][2 * hh][r] * adv[2 * hh] + acc[rt][2 * hh + 1][r] * adv[2 * hh + 1];
#pragma unroll
                for (int m = 8; m >= 1; m >>= 1) {
                    ps[hh] += __shfl_xor(ps[hh], m, 64);
                    pd[hh] += __shfl_xor(pd[hh], m, 64);
                }
            }
            if (rl == 0 && row < NN) {
#pragma unroll
                for (int hh = 0; hh < CT / 2; ++hh) {
                    const int hd = wave * (CT / 2) + hh;
                    als[(long long)hd * NN + row] = ps[hh];
                    ald[(long long)hd * NN + row] = pd[hh];
                }
            }
        }
    }
}

// edge-accumulate macro: GET(e) fetches csr entry e (LDS or global path)
#define ACC_EDGES(GET)                                                                 \
    {                                                                                  \
        int i = beg;                                                                   \
        for (; i + 7 < end; i += 8) {                                                  \
            int sn[8];                                                                 \
            float l[8];                                                                \
            ushort4 hv[8];                                                             \
            _Pragma("unroll") for (int k = 0; k < 8; ++k) sn[k] = GET(i + k);          \
            _Pragma("unroll") for (int k = 0; k < 8; ++k) l[k] = als_h[sn[k]] + aldd;  \
            _Pragma("unroll") for (int k = 0; k < 8; ++k) hv[k] =                      \
                *(const ushort4*)(slab + sn[k] * 32 + cl * 4);                         \
            _Pragma("unroll") for (int k = 0; k < 8; ++k) {                            \
                float lg = l[k] > 0.f ? l[k] : NEG_SLOPE * l[k];                       \
                const float wgt = __expf(lg);                                          \
                den += wgt;                                                            \
                a0 += wgt * b2f(hv[k].x);                                              \
                a1 += wgt * b2f(hv[k].y);                                              \
                a2 += wgt * b2f(hv[k].z);                                              \
                a3 += wgt * b2f(hv[k].w);                                              \
            }                                                                          \
        }                                                                              \
        for (; i + 3 < end; i += 4) {                                                  \
            int sn[4];                                                                 \
            float l[4];                                                                \
            ushort4 hv[4];                                                             \
            _Pragma("unroll") for (int k = 0; k < 4; ++k) sn[k] = GET(i + k);          \
            _Pragma("unroll") for (int k = 0; k < 4; ++k) l[k] = als_h[sn[k]] + aldd;  \
            _Pragma("unroll") for (int k = 0; k < 4; ++k) hv[k] =                      \
                *(const ushort4*)(slab + sn[k] * 32 + cl * 4);                         \
            _Pragma("unroll") for (int k = 0; k < 4; ++k) {                            \
                float lg = l[k] > 0.f ? l[k] : NEG_SLOPE * l[k];                       \
                const float wgt = __expf(lg);                                          \
                den += wgt;                                                            \
                a0 += wgt * b2f(hv[k].x);                                              \
                a1 += wgt * b2f(hv[k].y);                                              \
                a2 += wgt * b2f(hv[k].z);                                              \
                a3 += wgt * b2f(hv[k].w);                                              \
            }                                                                          \
        }                                                                              \
        for (; i < end; ++i) {                                                         \
            const int sn = GET(i);                                                     \
            float lg = als_h[sn] + aldd;                                               \
            lg = lg > 0.f ? lg : NEG_SLOPE * lg;                                       \
            const float wgt = __expf(lg);                                              \
            const ushort4 hv = *(const ushort4*)(slab + sn * 32 + cl * 4);             \
            den += wgt;                                                                \
            a0 += wgt * b2f(hv.x);                                                     \
            a1 += wgt * b2f(hv.y);                                                     \
            a2 += wgt * b2f(hv.z);                                                     \
            a3 += wgt * b2f(hv.w);                                                     \
        }                                                                              \
    }

#define LDSGET(E) lcsr[(E) - base]
#define GLBGET(E) csr[(E)]

// ============ XCD-sliced gather: LDS-staged csr window + sorted groups ============
// Block = one slice x one 256-node window (32 groups x 8 reps). csr segment of
// the window staged into LDS via coalesced NT loads (removes the csr dependent-
// chain latency AND keeps csr out of L2 so the 3.2 MB slab + als stay resident).
// Sorted lpos interleave (wave*64 + rep*8 + g) gives each wave near-equal-degree
// groups. Fallback to global csr if window exceeds WCAP (~never).
template <int OUT, int NSLICE, bool RELU>
__global__ void gathers_k(const int* __restrict__ start, const int* __restrict__ csr,
                          const int* __restrict__ perm,
                          const float* __restrict__ als, const float* __restrict__ ald,
                          const unsigned short* __restrict__ Hin,
                          const float* __restrict__ bias, unsigned short* __restrict__ outp) {
    __shared__ int lcsr[WCAP];
    __shared__ int lstart[257];
    __shared__ int lperm[256];
    constexpr int SUB = 8 / NSLICE;        // XCDs per slice
    const int xcd = blockIdx.x & 7;
    const int s = xcd / SUB;               // slice == head
    const int sub = xcd & (SUB - 1);
    const int w = (blockIdx.x >> 3) * SUB + sub;   // window id
    const int n0 = w * 256;
    const int nvalid = (NN - n0 < 256) ? (NN - n0) : 256;
    const int tid = threadIdx.x;
    const int base = start[n0];
    const int nedge = start[n0 + nvalid] - base;
    if (tid < nvalid) {
        lstart[tid] = start[n0 + tid];
        lperm[tid] = perm[n0 + tid];
    }
    if (tid == 0) lstart[nvalid] = base + nedge;
    const int nst = nedge < WCAP ? nedge : WCAP;
    for (int e = tid; e < nst; e += 256) lcsr[e] = __builtin_nontemporal_load(csr + base + e);
    __syncthreads();
    const int wv = tid >> 6;
    const int lane = tid & 63;
    const int g = lane >> 3;               // group within wave
    const int cl = lane & 7;               // channel lane (4 ch each)
    const bool inl = nedge <= WCAP;
    const float* als_h = als + s * NN;
    const float* ald_h = ald + s * NN;
    const unsigned short* slab = Hin + s * (NN * 32);
    const int c0 = s * 32 + cl * 4;
    const float b0 = bias[c0], b1 = bias[c0 + 1], b2 = bias[c0 + 2], b3 = bias[c0 + 3];
    for (int rep = 0; rep < 8; ++rep) {
        const int lpos = wv * 64 + rep * 8 + g;   // 8 groups of a wave take adjacent sorted nodes
        if (lpos >= nvalid) continue;
        const int d = lperm[lpos];
        const int li = d - n0;
        const int beg = lstart[li], end = lstart[li + 1];
        const float aldd = ald_h[d];
        float a0 = 0.f, a1 = 0.f, a2 = 0.f, a3 = 0.f, den = 0.f;
        if (inl) {
            ACC_EDGES(LDSGET)
        } else {
            ACC_EDGES(GLBGET)
        }
        const float inv = 1.f / (den + 1e-16f);
        float v0 = a0 * inv + b0;
        float v1 = a1 * inv + b1;
        float v2 = a2 * inv + b2;
        float v3 = a3 * inv + b3;
        if (RELU) {
            v0 = v0 > 0.f ? v0 : 0.f;
            v1 = v1 > 0.f ? v1 : 0.f;
            v2 = v2 > 0.f ? v2 : 0.f;
            v3 = v3 > 0.f ? v3 : 0.f;
        }
        unsigned long long pk =
            (unsigned long long)f2b(v0) |
            ((unsigned long long)f2b(v1) << 16) |
            ((unsigned long long)f2b(v2) << 32) |
            ((unsigned long long)f2b(v3) << 48);
        __builtin_nontemporal_store(pk, (unsigned long long*)(outp + d * OUT + c0));
    }
}

// ============ decode: XCD-sliced partial dots ============
__global__ void decode_s_k(const int* __restrict__ pei, const int* __restrict__ nei,
                           const unsigned short* __restrict__ z2, float* __restrict__ part) {
    const int s = blockIdx.x & 7;
    const int g = blockIdx.x >> 3;
    const int wave = threadIdx.x >> 6, lane = threadIdx.x & 63;
    const int slot = lane >> 3, cl = lane & 7;
    const int idx = g * 32 + wave * 8 + slot;
    if (idx >= 2 * E_DEC) return;
    int a, b;
    if (idx < E_DEC) {
        a = pei[idx];
        b = pei[E_DEC + idx];
    } else {
        const int j = idx - E_DEC;
        a = nei[j];
        b = nei[E_DEC + j];
    }
    const ushort4 ua = *(const ushort4*)(z2 + (long long)a * 256 + s * 32 + cl * 4);
    const ushort4 ub = *(const ushort4*)(z2 + (long long)b * 256 + s * 32 + cl * 4);
    float sum = b2f(ua.x) * b2f(ub.x) + b2f(ua.y) * b2f(ub.y) +
                b2f(ua.z) * b2f(ub.z) + b2f(ua.w) * b2f(ub.w);
    sum += __shfl_xor(sum, 4, 64);
    sum += __shfl_xor(sum, 2, 64);
    sum += __shfl_xor(sum, 1, 64);
    if (cl == 0) part[(long long)s * (2 * E_DEC) + idx] = sum;
}

__global__ void reduce_k(const float* __restrict__ part, float* __restrict__ out) {
    const int i = blockIdx.x * 256 + threadIdx.x;
    if (i >= 2 * E_DEC) return;
    float s = 0.f;
#pragma unroll
    for (int k = 0; k < 8; ++k) s += part[(long long)k * (2 * E_DEC) + i];
    out[i] = s;
}

extern "C" void kernel_launch(void* const* d_in, const int* in_sizes, int n_in,
                              void* d_out, int out_size, void* d_ws, size_t ws_size,
                              hipStream_t stream) {
    const float* x = (const float*)d_in[0];
    const int* ei = (const int*)d_in[1];
    const int* pei = (const int*)d_in[2];
    const int* nei = (const int*)d_in[3];
    const float* W1 = (const float*)d_in[4];
    const float* as1 = (const float*)d_in[5];
    const float* ad1 = (const float*)d_in[6];
    const float* b1 = (const float*)d_in[7];
    const float* W2 = (const float*)d_in[8];
    const float* as2 = (const float*)d_in[9];
    const float* ad2 = (const float*)d_in[10];
    const float* b2 = (const float*)d_in[11];
    float* out = (float*)d_out;

    // ---- workspace layout ----
    unsigned short* h1 = (unsigned short*)d_ws;              // [4][NN][32] slab-major
    unsigned short* h2 = h1 + (long long)NN * 128;           // [8][NN][32] slab-major
    unsigned short* z2 = h2 + (long long)NN * 256;           // NN*256 row-major
    unsigned short* z1 = z2 + (long long)NN * 256;           // NN*128 row-major
    unsigned short* wp1 = z1 + (long long)NN * 128;          // 128*128
    unsigned short* wp2 = wp1 + 128 * 128;                   // 128*256
    float* als1 = (float*)(wp2 + 128 * 256);                 // [H1][NN] head-major
    float* ald1 = als1 + NN * H1;
    float* als2 = ald1 + NN * H1;                            // [H2][NN] head-major
    float* ald2 = als2 + NN * H2;
    float* part = ald2 + NN * H2;                            // 8 * 2*E_DEC
    int* counts_p = (int*)(part + 8 * 2 * E_DEC);            // 8*NN
    int* start = counts_p + 8 * NN;                          // NN+1
    int* offs = start + NN + 1;                              // 8*NN
    int* rank = offs + 8 * NN;                               // EE
    int* bsum = rank + EE;                                   // 256
    int* csr = bsum + 256;                                   // ET
    int* perm = csr + ET;                                    // NN (block-local degree sort)
    int* probe = perm + NN;                                  // 1 (never written)

    const int NB = (NN + 255) / 256;  // 196 windows

    // ---- CSR build + W pack + block-local degree sort ----
    hist_pack_k<<<HIST_BLOCKS + PACK_BLOCKS, 256, 0, stream>>>(
        ei, counts_p, probe, rank, W1, wp1, W2, wp2);
    scan1_k<<<NB, 256, 0, stream>>>(counts_p, probe, bsum);
    scan2_k<<<1, 256, 0, stream>>>(bsum, NB, start);
    scan3_k<<<NB, 256, 0, stream>>>(counts_p, probe, bsum, start, offs, csr, perm);
    scatter_k<<<HIST_BLOCKS, 256, 0, stream>>>(ei, rank, offs, csr);

    // ---- conv1 ----
    gemm_k<128, H1, 2, true><<<(NN + 63) / 64, 256, 0, stream>>>(
        x, wp1, as1, ad1, h1, als1, ald1);
    // 4 slices, 2 XCDs each -> 98 block-rows cover 196 windows
    gathers_k<128, 4, true><<<8 * ((NB + 1) / 2), 256, 0, stream>>>(
        start, csr, perm, als1, ald1, h1, b1, z1);

    // ---- conv2 ----
    gemm_k<256, H2, 4, false><<<(NN + 63) / 64, 256, 0, stream>>>(
        z1, wp2, as2, ad2, h2, als2, ald2);
    // 8 slices, 1 XCD each -> 196 block-rows
    gathers_k<256, 8, false><<<8 * NB, 256, 0, stream>>>(
        start, csr, perm, als2, ald2, h2, b2, z2);

    // ---- decode ----
    decode_s_k<<<8 * ((2 * E_DEC + 31) / 32), 256, 0, stream>>>(pei, nei, z2, part);
    reduce_k<<<(2 * E_DEC + 255) / 256, 256, 0, stream>>>(part, out);
}

// Round 9
// 357.410 us; speedup vs baseline: 1.2522x; 1.0405x over previous
//
#include <hip/hip_runtime.h>
#include <hip/hip_bf16.h>

#define NN 50000
#define EE 800000
#define ET (EE + NN)
#define F_IN 128
#define HID 32
#define H1 4
#define H2 8
#define E_DEC 100000
#define NEG_SLOPE 0.2f
#define WN 128                      // nodes per gather window
#define NW ((NN + WN - 1) / WN)     // 391 windows
#define WCAP 2944                   // staged csr cap per window (mean 2176, +17 sigma)

typedef __attribute__((ext_vector_type(8))) short short8;
typedef __attribute__((ext_vector_type(4))) float floatx4;

__device__ __forceinline__ unsigned short f2b(float f) {
    __hip_bfloat16 h = __float2bfloat16(f);
    return *reinterpret_cast<unsigned short*>(&h);
}
__device__ __forceinline__ float b2f(unsigned short u) {
    return __uint_as_float(((unsigned int)u) << 16);
}

// ============ merged: XCD-local histogram+rank + pack W1 + pack W2 ============
__device__ __forceinline__ void packW_one(const float* __restrict__ W,
                                          unsigned short* __restrict__ Wp, int OUT, int id) {
    const int ctg = id >> 8;
    const int ln = id & 63;
    const int col = ctg * 16 + (ln & 15);
    const int k0 = ((id >> 6) & 3) * 32 + ((ln >> 4) & 3) * 8;
    ushort4 lo, hi;
    lo.x = f2b(W[(k0 + 0) * OUT + col]);
    lo.y = f2b(W[(k0 + 1) * OUT + col]);
    lo.z = f2b(W[(k0 + 2) * OUT + col]);
    lo.w = f2b(W[(k0 + 3) * OUT + col]);
    hi.x = f2b(W[(k0 + 4) * OUT + col]);
    hi.y = f2b(W[(k0 + 5) * OUT + col]);
    hi.z = f2b(W[(k0 + 6) * OUT + col]);
    hi.w = f2b(W[(k0 + 7) * OUT + col]);
    ((ushort4*)Wp)[id * 2] = lo;
    ((ushort4*)Wp)[id * 2 + 1] = hi;
}

#define HIST_BLOCKS ((EE / 4 + 255) / 256)   // 782
#define PACK_BLOCKS ((6144 + 255) / 256)     // 24

__global__ void hist_pack_k(const int* __restrict__ ei, int* __restrict__ counts_p,
                            const int* __restrict__ probe, int* __restrict__ rank,
                            const float* __restrict__ W1, unsigned short* __restrict__ wp1,
                            const float* __restrict__ W2, unsigned short* __restrict__ wp2) {
    if (blockIdx.x < HIST_BLOCKS) {
        const int t = blockIdx.x * 256 + threadIdx.x;
        if (t >= EE / 4) return;
        const int pv = probe[0];
        int* cp = counts_p + (blockIdx.x & 7) * NN;
        const int4 d4 = ((const int4*)(ei + EE))[t];
        int4 r4;
        r4.x = atomicAdd(&cp[d4.x], 1) - pv;
        r4.y = atomicAdd(&cp[d4.y], 1) - pv;
        r4.z = atomicAdd(&cp[d4.z], 1) - pv;
        r4.w = atomicAdd(&cp[d4.w], 1) - pv;
        ((int4*)rank)[t] = r4;
    } else {
        const int id = (blockIdx.x - HIST_BLOCKS) * 256 + threadIdx.x;
        if (id < 2048) packW_one(W1, wp1, 128, id);
        else if (id < 6144) packW_one(W2, wp2, 256, id - 2048);
    }
}

// ============ scan1: per-window (128-node) degree sums ============
__global__ void scan1_k(const int* __restrict__ counts_p, const int* __restrict__ probe,
                        int* __restrict__ bsum) {
    __shared__ int sh[WN];
    const unsigned pv = (unsigned)probe[0];
    int t = threadIdx.x;
    int i = blockIdx.x * WN + t;
    int deg = 0;
    if (i < NN) {
        unsigned sum = 0;
#pragma unroll
        for (int s = 0; s < 8; ++s) sum += (unsigned)counts_p[s * NN + i];
        deg = (int)(sum - 8u * pv) + 1;
    }
    sh[t] = deg;
    __syncthreads();
    for (int off = WN / 2; off > 0; off >>= 1) {
        if (t < off) sh[t] += sh[t + off];
        __syncthreads();
    }
    if (t == 0) bsum[blockIdx.x] = sh[0];
}

// scan2: 512 threads to cover NW=391 window sums
__global__ void scan2_k(int* __restrict__ bsum, int nb, int* __restrict__ start) {
    __shared__ int sh[512];
    int t = threadIdx.x;
    int v = (t < nb) ? bsum[t] : 0;
    sh[t] = v;
    __syncthreads();
    for (int off = 1; off < 512; off <<= 1) {
        int u = (t >= off) ? sh[t - off] : 0;
        __syncthreads();
        sh[t] += u;
        __syncthreads();
    }
    if (t < nb) bsum[t] = sh[t] - v;
    if (t == 0) start[NN] = ET;
}

// ============ scan3: start/offs/self-loop + 128-node-window degree counting-sort ============
__global__ void scan3_k(const int* __restrict__ counts_p, const int* __restrict__ probe,
                        const int* __restrict__ bsum, int* __restrict__ start,
                        int* __restrict__ offs, int* __restrict__ csr,
                        int* __restrict__ perm) {
    __shared__ int sh[WN];
    __shared__ int lhist[256];
    __shared__ int lpre[256];
    const unsigned pv = (unsigned)probe[0];
    int t = threadIdx.x;                 // 0..127
    int i = blockIdx.x * WN + t;
    lhist[t] = 0;
    lhist[t + 128] = 0;
    int part[8];
    int deg = 0;
    if (i < NN) {
        deg = 1;
#pragma unroll
        for (int s = 0; s < 8; ++s) {
            part[s] = (int)((unsigned)counts_p[s * NN + i] - pv);
            deg += part[s];
        }
    }
    const int bin = deg < 255 ? deg : 255;
    sh[t] = deg;
    __syncthreads();
    int lrank = 0;
    if (i < NN) lrank = atomicAdd(&lhist[bin], 1);
    for (int off = 1; off < WN; off <<= 1) {
        int u = (t >= off) ? sh[t - off] : 0;
        __syncthreads();
        sh[t] += u;
        __syncthreads();
    }
    int excl = sh[t] - deg + bsum[blockIdx.x];
    if (i < NN) {
        start[i] = excl;
        int o = excl;
#pragma unroll
        for (int s = 0; s < 8; ++s) {
            offs[s * NN + i] = o;
            o += part[s];
        }
        csr[o] = i;   // self-loop last
    }
    // 256-bin inclusive scan, 2 bins per thread
    __syncthreads();
    lpre[t] = lhist[t];
    lpre[t + 128] = lhist[t + 128];
    __syncthreads();
    for (int off = 1; off < 256; off <<= 1) {
        int u0 = (t >= off) ? lpre[t - off] : 0;
        int u1 = (t + 128 >= off) ? lpre[t + 128 - off] : 0;
        __syncthreads();
        lpre[t] += u0;
        lpre[t + 128] += u1;
        __syncthreads();
    }
    if (i < NN) {
        const int lpos = lpre[bin] - lhist[bin] + lrank;   // exclusive base + rank
        perm[blockIdx.x * WN + lpos] = i;
    }
}

// ============ scatter: rank+offs based, NO atomics, XCD-affine offs reads ============
__global__ void scatter_k(const int* __restrict__ ei, const int* __restrict__ rank,
                          const int* __restrict__ offs, int* __restrict__ csr) {
    const int t = blockIdx.x * 256 + threadIdx.x;
    if (t >= EE / 4) return;
    const int* off = offs + (blockIdx.x & 7) * NN;
    const int4 s4 = ((const int4*)ei)[t];
    const int4 d4 = ((const int4*)(ei + EE))[t];
    const int4 r4 = ((const int4*)rank)[t];
    csr[off[d4.x] + r4.x] = s4.x;
    csr[off[d4.y] + r4.y] = s4.y;
    csr[off[d4.z] + r4.z] = s4.z;
    csr[off[d4.w] + r4.w] = s4.w;
}

// ============ MFMA GEMM + fused al epilogue ============
// Hout SLAB-MAJOR [head][NN][32ch]; als/ald HEAD-MAJOR [H][NN].
template <int OUT, int H, int CT, bool F32IN>
__global__ void gemm_k(const void* __restrict__ Xin, const unsigned short* __restrict__ Wp,
                       const float* __restrict__ a_src, const float* __restrict__ a_dst,
                       unsigned short* __restrict__ Hout, float* __restrict__ als,
                       float* __restrict__ ald) {
    const int wave = threadIdx.x >> 6;
    const int lane = threadIdx.x & 63;
    const int quad = lane >> 4;
    const int rl = lane & 15;
    const int r0 = blockIdx.x * 64;
    floatx4 acc[4][CT];
#pragma unroll
    for (int rt = 0; rt < 4; ++rt)
#pragma unroll
        for (int ct = 0; ct < CT; ++ct) acc[rt][ct] = {0.f, 0.f, 0.f, 0.f};

#pragma unroll
    for (int ks = 0; ks < 4; ++ks) {
        short8 a[4];
        const int c0k = ks * 32 + quad * 8;
#pragma unroll
        for (int rt = 0; rt < 4; ++rt) {
            int row = r0 + rt * 16 + rl;
            row = row < NN ? row : NN - 1;
            if (F32IN) {
                const float4* xp =
                    (const float4*)((const float*)Xin + (long long)row * 128 + c0k);
                const float4 v0 = xp[0];
                const float4 v1 = xp[1];
                short8 tt;
                tt[0] = (short)f2b(v0.x);
                tt[1] = (short)f2b(v0.y);
                tt[2] = (short)f2b(v0.z);
                tt[3] = (short)f2b(v0.w);
                tt[4] = (short)f2b(v1.x);
                tt[5] = (short)f2b(v1.y);
                tt[6] = (short)f2b(v1.z);
                tt[7] = (short)f2b(v1.w);
                a[rt] = tt;
            } else {
                a[rt] = *(const short8*)((const unsigned short*)Xin +
                                         (long long)row * 128 + c0k);
            }
        }
#pragma unroll
        for (int ct = 0; ct < CT; ++ct) {
            const int ctg = wave * CT + ct;
            const short8 b = *(const short8*)(Wp + (((ctg * 4 + ks) * 64 + lane) << 3));
#pragma unroll
            for (int rt = 0; rt < 4; ++rt)
                acc[rt][ct] = __builtin_amdgcn_mfma_f32_16x16x32_bf16(a[rt], b, acc[rt][ct], 0, 0, 0);
        }
    }
#pragma unroll
    for (int rt = 0; rt < 4; ++rt) {
        const int rowbase = r0 + rt * 16 + quad * 4;
#pragma unroll
        for (int ct = 0; ct < CT; ++ct) {
            const int col = (wave * CT + ct) * 16 + rl;
            unsigned short* hp = Hout + (long long)(col >> 5) * NN * 32 + (col & 31);
#pragma unroll
            for (int r = 0; r < 4; ++r) {
                const int row = rowbase + r;
                if (row < NN) hp[(long long)row * 32] = f2b(acc[rt][ct][r]);
            }
        }
    }
    float asv[CT], adv[CT];
#pragma unroll
    for (int ct = 0; ct < CT; ++ct) {
        const int col = (wave * CT + ct) * 16 + rl;
        asv[ct] = a_src[col];
        adv[ct] = a_dst[col];
    }
#pragma unroll
    for (int rt = 0; rt < 4; ++rt) {
#pragma unroll
        for (int r = 0; r < 4; ++r) {
            const int row = r0 + rt * 16 + quad * 4 + r;
            float ps[CT / 2], pd[CT / 2];
#pragma unroll
            for (int hh = 0; hh < CT / 2; ++hh) {
                ps[hh] = acc[rt][2 * hh][r] * asv[2 * hh] + acc[rt][2 * hh + 1][r] * asv[2 * hh + 1];
                pd[hh] = acc[rt][2 * hh][r] * adv[2 * hh] + acc[rt][2 * hh + 1][r] * adv[2 * hh + 1];
#pragma unroll
                for (int m = 8; m >= 1; m >>= 1) {
                    ps[hh] += __shfl_xor(ps[hh], m, 64);
                    pd[hh] += __shfl_xor(pd[hh], m, 64);
                }
            }
            if (rl == 0 && row < NN) {
#pragma unroll
                for (int hh = 0; hh < CT / 2; ++hh) {
                    const int hd = wave * (CT / 2) + hh;
                    als[(long long)hd * NN + row] = ps[hh];
                    ald[(long long)hd * NN + row] = pd[hh];
                }
            }
        }
    }
}

// edge-accumulate macro: GET(e) fetches csr entry e (LDS or global path)
#define ACC_EDGES(GET)                                                                 \
    {                                                                                  \
        int i = beg;                                                                   \
        for (; i + 7 < end; i += 8) {                                                  \
            int sn[8];                                                                 \
            float l[8];                                                                \
            ushort4 hv[8];                                                             \
            _Pragma("unroll") for (int k = 0; k < 8; ++k) sn[k] = GET(i + k);          \
            _Pragma("unroll") for (int k = 0; k < 8; ++k) l[k] = als_h[sn[k]] + aldd;  \
            _Pragma("unroll") for (int k = 0; k < 8; ++k) hv[k] =                      \
                *(const ushort4*)(slab + sn[k] * 32 + cl * 4);                         \
            _Pragma("unroll") for (int k = 0; k < 8; ++k) {                            \
                float lg = l[k] > 0.f ? l[k] : NEG_SLOPE * l[k];                       \
                const float wgt = __expf(lg);                                          \
                den += wgt;                                                            \
                a0 += wgt * b2f(hv[k].x);                                              \
                a1 += wgt * b2f(hv[k].y);                                              \
                a2 += wgt * b2f(hv[k].z);                                              \
                a3 += wgt * b2f(hv[k].w);                                              \
            }                                                                          \
        }                                                                              \
        for (; i + 3 < end; i += 4) {                                                  \
            int sn[4];                                                                 \
            float l[4];                                                                \
            ushort4 hv[4];                                                             \
            _Pragma("unroll") for (int k = 0; k < 4; ++k) sn[k] = GET(i + k);          \
            _Pragma("unroll") for (int k = 0; k < 4; ++k) l[k] = als_h[sn[k]] + aldd;  \
            _Pragma("unroll") for (int k = 0; k < 4; ++k) hv[k] =                      \
                *(const ushort4*)(slab + sn[k] * 32 + cl * 4);                         \
            _Pragma("unroll") for (int k = 0; k < 4; ++k) {                            \
                float lg = l[k] > 0.f ? l[k] : NEG_SLOPE * l[k];                       \
                const float wgt = __expf(lg);                                          \
                den += wgt;                                                            \
                a0 += wgt * b2f(hv[k].x);                                              \
                a1 += wgt * b2f(hv[k].y);                                              \
                a2 += wgt * b2f(hv[k].z);                                              \
                a3 += wgt * b2f(hv[k].w);                                              \
            }                                                                          \
        }                                                                              \
        for (; i < end; ++i) {                                                         \
            const int sn = GET(i);                                                     \
            float lg = als_h[sn] + aldd;                                               \
            lg = lg > 0.f ? lg : NEG_SLOPE * lg;                                       \
            const float wgt = __expf(lg);                                              \
            const ushort4 hv = *(const ushort4*)(slab + sn * 32 + cl * 4);             \
            den += wgt;                                                                \
            a0 += wgt * b2f(hv.x);                                                     \
            a1 += wgt * b2f(hv.y);                                                     \
            a2 += wgt * b2f(hv.z);                                                     \
            a3 += wgt * b2f(hv.w);                                                     \
        }                                                                              \
    }

#define LDSGET(E) lcsr[(E) - base]
#define GLBGET(E) csr[(E)]

// ============ XCD-sliced gather: 128-node LDS windows, 12.8 KB/block ============
// Half-size windows vs r8: LDS 26->12.8 KB and grid 1568->3128 blocks, so more
// blocks/CU resident AND real backfill (12.2 blocks/CU vs one residency round).
// lpos = rep*32 + wv*8 + g: wave's 8 groups adjacent in sorted order (equal
// degree), degree quartiles spread across waves (intra-block balance).
template <int OUT, int NSLICE, bool RELU>
__global__ void gathers_k(const int* __restrict__ start, const int* __restrict__ csr,
                          const int* __restrict__ perm,
                          const float* __restrict__ als, const float* __restrict__ ald,
                          const unsigned short* __restrict__ Hin,
                          const float* __restrict__ bias, unsigned short* __restrict__ outp) {
    __shared__ int lcsr[WCAP];
    __shared__ int lstart[WN + 1];
    __shared__ int lperm[WN];
    constexpr int SUB = 8 / NSLICE;        // XCDs per slice
    const int xcd = blockIdx.x & 7;
    const int s = xcd / SUB;               // slice == head
    const int sub = xcd & (SUB - 1);
    const int w = (blockIdx.x >> 3) * SUB + sub;   // window id
    if (w >= NW) return;
    const int n0 = w * WN;
    const int nvalid = (NN - n0 < WN) ? (NN - n0) : WN;
    const int tid = threadIdx.x;
    const int base = start[n0];
    const int nedge = start[n0 + nvalid] - base;
    if (tid < nvalid) {
        lstart[tid] = start[n0 + tid];
        lperm[tid] = perm[n0 + tid];
    }
    if (tid == 0) lstart[nvalid] = base + nedge;
    const int nst = nedge < WCAP ? nedge : WCAP;
    for (int e = tid; e < nst; e += 256) lcsr[e] = __builtin_nontemporal_load(csr + base + e);
    __syncthreads();
    const int wv = tid >> 6;
    const int lane = tid & 63;
    const int g = lane >> 3;               // group within wave
    const int cl = lane & 7;               // channel lane (4 ch each)
    const bool inl = nedge <= WCAP;
    const float* als_h = als + s * NN;
    const float* ald_h = ald + s * NN;
    const unsigned short* slab = Hin + s * (NN * 32);
    const int c0 = s * 32 + cl * 4;
    const float b0 = bias[c0], b1 = bias[c0 + 1], b2 = bias[c0 + 2], b3 = bias[c0 + 3];
#pragma unroll
    for (int rep = 0; rep < WN / 32; ++rep) {
        const int lpos = rep * 32 + wv * 8 + g;
        if (lpos >= nvalid) continue;
        const int d = lperm[lpos];
        const int li = d - n0;
        const int beg = lstart[li], end = lstart[li + 1];
        const float aldd = ald_h[d];
        float a0 = 0.f, a1 = 0.f, a2 = 0.f, a3 = 0.f, den = 0.f;
        if (inl) {
            ACC_EDGES(LDSGET)
        } else {
            ACC_EDGES(GLBGET)
        }
        const float inv = 1.f / (den + 1e-16f);
        float v0 = a0 * inv + b0;
        float v1 = a1 * inv + b1;
        float v2 = a2 * inv + b2;
        float v3 = a3 * inv + b3;
        if (RELU) {
            v0 = v0 > 0.f ? v0 : 0.f;
            v1 = v1 > 0.f ? v1 : 0.f;
            v2 = v2 > 0.f ? v2 : 0.f;
            v3 = v3 > 0.f ? v3 : 0.f;
        }
        unsigned long long pk =
            (unsigned long long)f2b(v0) |
            ((unsigned long long)f2b(v1) << 16) |
            ((unsigned long long)f2b(v2) << 32) |
            ((unsigned long long)f2b(v3) << 48);
        __builtin_nontemporal_store(pk, (unsigned long long*)(outp + d * OUT + c0));
    }
}

// ============ decode: XCD-sliced partial dots ============
__global__ void decode_s_k(const int* __restrict__ pei, const int* __restrict__ nei,
                           const unsigned short* __restrict__ z2, float* __restrict__ part) {
    const int s = blockIdx.x & 7;
    const int g = blockIdx.x >> 3;
    const int wave = threadIdx.x >> 6, lane = threadIdx.x & 63;
    const int slot = lane >> 3, cl = lane & 7;
    const int idx = g * 32 + wave * 8 + slot;
    if (idx >= 2 * E_DEC) return;
    int a, b;
    if (idx < E_DEC) {
        a = pei[idx];
        b = pei[E_DEC + idx];
    } else {
        const int j = idx - E_DEC;
        a = nei[j];
        b = nei[E_DEC + j];
    }
    const ushort4 ua = *(const ushort4*)(z2 + (long long)a * 256 + s * 32 + cl * 4);
    const ushort4 ub = *(const ushort4*)(z2 + (long long)b * 256 + s * 32 + cl * 4);
    float sum = b2f(ua.x) * b2f(ub.x) + b2f(ua.y) * b2f(ub.y) +
                b2f(ua.z) * b2f(ub.z) + b2f(ua.w) * b2f(ub.w);
    sum += __shfl_xor(sum, 4, 64);
    sum += __shfl_xor(sum, 2, 64);
    sum += __shfl_xor(sum, 1, 64);
    if (cl == 0) part[(long long)s * (2 * E_DEC) + idx] = sum;
}

__global__ void reduce_k(const float* __restrict__ part, float* __restrict__ out) {
    const int i = blockIdx.x * 256 + threadIdx.x;
    if (i >= 2 * E_DEC) return;
    float s = 0.f;
#pragma unroll
    for (int k = 0; k < 8; ++k) s += part[(long long)k * (2 * E_DEC) + i];
    out[i] = s;
}

extern "C" void kernel_launch(void* const* d_in, const int* in_sizes, int n_in,
                              void* d_out, int out_size, void* d_ws, size_t ws_size,
                              hipStream_t stream) {
    const float* x = (const float*)d_in[0];
    const int* ei = (const int*)d_in[1];
    const int* pei = (const int*)d_in[2];
    const int* nei = (const int*)d_in[3];
    const float* W1 = (const float*)d_in[4];
    const float* as1 = (const float*)d_in[5];
    const float* ad1 = (const float*)d_in[6];
    const float* b1 = (const float*)d_in[7];
    const float* W2 = (const float*)d_in[8];
    const float* as2 = (const float*)d_in[9];
    const float* ad2 = (const float*)d_in[10];
    const float* b2 = (const float*)d_in[11];
    float* out = (float*)d_out;

    // ---- workspace layout ----
    unsigned short* h1 = (unsigned short*)d_ws;              // [4][NN][32] slab-major
    unsigned short* h2 = h1 + (long long)NN * 128;           // [8][NN][32] slab-major
    unsigned short* z2 = h2 + (long long)NN * 256;           // NN*256 row-major
    unsigned short* z1 = z2 + (long long)NN * 256;           // NN*128 row-major
    unsigned short* wp1 = z1 + (long long)NN * 128;          // 128*128
    unsigned short* wp2 = wp1 + 128 * 128;                   // 128*256
    float* als1 = (float*)(wp2 + 128 * 256);                 // [H1][NN] head-major
    float* ald1 = als1 + NN * H1;
    float* als2 = ald1 + NN * H1;                            // [H2][NN] head-major
    float* ald2 = als2 + NN * H2;
    float* part = ald2 + NN * H2;                            // 8 * 2*E_DEC
    int* counts_p = (int*)(part + 8 * 2 * E_DEC);            // 8*NN
    int* start = counts_p + 8 * NN;                          // NN+1
    int* offs = start + NN + 1;                              // 8*NN
    int* rank = offs + 8 * NN;                               // EE
    int* bsum = rank + EE;                                   // 512 (NW=391 window sums)
    int* csr = bsum + 512;                                   // ET
    int* perm = csr + ET;                                    // NN (window-local degree sort)
    int* probe = perm + NN;                                  // 1 (never written)

    // ---- CSR build + W pack + window-local degree sort ----
    hist_pack_k<<<HIST_BLOCKS + PACK_BLOCKS, 256, 0, stream>>>(
        ei, counts_p, probe, rank, W1, wp1, W2, wp2);
    scan1_k<<<NW, WN, 0, stream>>>(counts_p, probe, bsum);
    scan2_k<<<1, 512, 0, stream>>>(bsum, NW, start);
    scan3_k<<<NW, WN, 0, stream>>>(counts_p, probe, bsum, start, offs, csr, perm);
    scatter_k<<<HIST_BLOCKS, 256, 0, stream>>>(ei, rank, offs, csr);

    // ---- conv1 ----
    gemm_k<128, H1, 2, true><<<(NN + 63) / 64, 256, 0, stream>>>(
        x, wp1, as1, ad1, h1, als1, ald1);
    // 4 slices, 2 XCDs each: rows cover windows in pairs
    gathers_k<128, 4, true><<<8 * ((NW + 1) / 2), 256, 0, stream>>>(
        start, csr, perm, als1, ald1, h1, b1, z1);

    // ---- conv2 ----
    gemm_k<256, H2, 4, false><<<(NN + 63) / 64, 256, 0, stream>>>(
        z1, wp2, as2, ad2, h2, als2, ald2);
    // 8 slices, 1 XCD each: one block per (slice, window)
    gathers_k<256, 8, false><<<8 * NW, 256, 0, stream>>>(
        start, csr, perm, als2, ald2, h2, b2, z2);

    // ---- decode ----
    decode_s_k<<<8 * ((2 * E_DEC + 31) / 32), 256, 0, stream>>>(pei, nei, z2, part);
    reduce_k<<<(2 * E_DEC + 255) / 256, 256, 0, stream>>>(part, out);
}